// Round 2
// baseline (124.922 us; speedup 1.0000x reference)
//
#include <hip/hip_runtime.h>
#include <math.h>

// x: (256, 224, 224) f32.  HW = 50176 = 7*1792 v4*4;  1792 v4 = 7*256.
#define HW       50176
#define NV4      12544      // float4 per row
#define CHUNKS   7          // blocks per row in K1/K3
#define CV4      1792       // float4 per chunk (= 7 * 256)
#define TPB      256

// ---- ws layout (bytes) ----
// sums   : double[1792]  @ 0
// sumls  : double[1792]  @ 14336
// mins   : float [1792]  @ 28672
// params : float [256*12]@ 35840   {rmin,k,invth,c0..c7,pad}
#define WS_SUM(ws)    ((double*)((char*)(ws)))
#define WS_SUML(ws)   ((double*)((char*)(ws) + 14336))
#define WS_MIN(ws)    ((float*)((char*)(ws) + 28672))
#define WS_PAR(ws)    ((float*)((char*)(ws) + 35840))

__device__ __forceinline__ float waveReduceMin(float v) {
#pragma unroll
    for (int o = 32; o > 0; o >>= 1) v = fminf(v, __shfl_down(v, o, 64));
    return v;
}
__device__ __forceinline__ double waveReduceSumD(double v) {
#pragma unroll
    for (int o = 32; o > 0; o >>= 1) v += __shfl_down(v, o, 64);
    return v;
}

__device__ __forceinline__ float digamma_f(float x) {
    float r = 0.0f;
    while (x < 6.0f) { r -= 1.0f / x; x += 1.0f; }
    float f = 1.0f / (x * x);
    float ser = f * (1.0f/12.0f - f * (1.0f/120.0f - f * (1.0f/252.0f - f * (1.0f/240.0f - f * (1.0f/132.0f)))));
    return r + logf(x) - 0.5f / x - ser;
}

__device__ __forceinline__ float trigamma_ref(float x) {
    float z = x + 1.0f;
    float zz = z * z;
    float a = 0.2f - 1.0f / (7.0f * zz);
    float b = 1.0f - a / zz;
    float c = 1.0f + b / (3.0f * z);
    float d = 1.0f + c / (2.0f * z);
    return d / z + 1.0f / (x * x);
}

// ============ K1: per-chunk partial min / sum / sumlog ============
__global__ void __launch_bounds__(TPB)
k1_stats(const float* __restrict__ x, void* __restrict__ ws) {
    const int bid  = blockIdx.x;            // row*7 + chunk
    const int row  = bid / CHUNKS;
    const int chnk = bid - row * CHUNKS;
    const int tid  = threadIdx.x;
    const float4* __restrict__ xr =
        (const float4*)(x) + (size_t)row * NV4 + (size_t)chnk * CV4;

    float pmin = INFINITY;
    float psum = 0.0f;
    float psl  = 0.0f;
#pragma unroll
    for (int j = 0; j < 7; ++j) {
        float4 v = xr[j * TPB + tid];
        pmin = fminf(pmin, fminf(fminf(v.x, v.y), fminf(v.z, v.w)));
        psum += (v.x + v.y) + (v.z + v.w);
        // note: sum/sumlog of raw x is NOT what we need; min isn't known yet.
        // We accumulate raw sum here; the (x - min + 2e-7) shift is linear so
        // sum_xm = sum_x - HW*min + HW*2e-7 can be fixed up in K2.  But sumlog
        // is NOT linear -> we must log the shifted value.  Min is global per
        // row, unknown in this pass.  So instead: K1 only does min+sum, and
        // sumlog needs a second pass?  No -- see below: we do sumlog in K3's
        // sibling pass.  To keep one pass, we exploit that log(x - min + eps)
        // requires min.  Solution used here: two-stage within K1 is impossible,
        // so sumlog partials are computed in K2b... (see k1b_sumlog)
        (void)psl;
    }
    // block reduce min and sum
    pmin = waveReduceMin(pmin);
    double dsum = waveReduceSumD((double)psum);

    __shared__ float  smin[4];
    __shared__ double ssum[4];
    const int wid = tid >> 6, lane = tid & 63;
    if (lane == 0) { smin[wid] = pmin; ssum[wid] = dsum; }
    __syncthreads();
    if (tid == 0) {
        float mm = fminf(fminf(smin[0], smin[1]), fminf(smin[2], smin[3]));
        double ss = (ssum[0] + ssum[1]) + (ssum[2] + ssum[3]);
        WS_MIN(ws)[bid] = mm;
        WS_SUM(ws)[bid] = ss;
    }
}

// ============ K1b: finalize per-row min into params[row*12+0] ============
__global__ void __launch_bounds__(64)
k1b_min(void* __restrict__ ws) {
    const int row = blockIdx.x * 64 + threadIdx.x;   // 4 blocks * 64
    if (row >= 256) return;
    const float* mins = WS_MIN(ws);
    float mm = INFINITY;
#pragma unroll
    for (int i = 0; i < CHUNKS; ++i) mm = fminf(mm, mins[row * CHUNKS + i]);
    WS_PAR(ws)[row * 12 + 0] = mm;
}

// ============ K1c: per-chunk partial sumlog of (x - rmin + 2e-7) ============
__global__ void __launch_bounds__(TPB)
k1c_sumlog(const float* __restrict__ x, void* __restrict__ ws) {
    const int bid  = blockIdx.x;
    const int row  = bid / CHUNKS;
    const int chnk = bid - row * CHUNKS;
    const int tid  = threadIdx.x;
    const float rmin = WS_PAR(ws)[row * 12 + 0];
    const float4* __restrict__ xr =
        (const float4*)(x) + (size_t)row * NV4 + (size_t)chnk * CV4;

    float psl = 0.0f;
#pragma unroll
    for (int j = 0; j < 7; ++j) {
        float4 v = xr[j * TPB + tid];
        float a0 = (v.x - rmin + 1e-7f) + 1e-7f;
        float a1 = (v.y - rmin + 1e-7f) + 1e-7f;
        float a2 = (v.z - rmin + 1e-7f) + 1e-7f;
        float a3 = (v.w - rmin + 1e-7f) + 1e-7f;
        psl += (__logf(a0) + __logf(a1)) + (__logf(a2) + __logf(a3));
    }
    double dsl = waveReduceSumD((double)psl);
    __shared__ double ssl[4];
    const int wid = tid >> 6, lane = tid & 63;
    if (lane == 0) ssl[wid] = dsl;
    __syncthreads();
    if (tid == 0)
        WS_SUML(ws)[bid] = (ssl[0] + ssl[1]) + (ssl[2] + ssl[3]);
}

// ============ K2: finalize stats, Newton, Gamma, coefficients ============
__global__ void __launch_bounds__(64)
k2_solve(void* __restrict__ ws) {
    const int row = blockIdx.x * 64 + threadIdx.x;   // 4 blocks * 64
    if (row >= 256) return;
    float* par = WS_PAR(ws) + row * 12;
    const float rmin = par[0];

    double ts = 0.0, tl = 0.0;
#pragma unroll
    for (int i = 0; i < CHUNKS; ++i) {
        ts += WS_SUM(ws)[row * CHUNKS + i];
        tl += WS_SUML(ws)[row * CHUNKS + i];
    }
    // shift raw sum: xm = x - rmin + 2e-7
    ts = ts - (double)HW * ((double)rmin - 2e-7);
    const double meand = ts / (double)HW;
    const double mlogd = tl / (double)HW;
    float s = (float)(log(meand) - mlogd);

    float s3 = s - 3.0f;
    float rt = sqrtf(s3 * s3 + 24.0f * s);
    float k  = (3.0f - s + rt) / (12.0f * s) + 1e-7f;
    for (int it = 0; it < 10; ++it) {
        float nm = logf(k) - digamma_f(k) - s;
        float dn = 1.0f / k - trigamma_ref(k);
        k = k - nm / dn;
    }
    if (k < 1e-7f) k = 1e-7f;
    if (k > 18.0f) k = 18.0f;

    const double CH[8] = {676.5203681218851, -1259.1392167224028, 771.3234287776531,
                          -176.6150291621406, 12.507343278686905, -0.13857109526572012,
                          9.984369578019572e-06, 1.5056327351493116e-07};
    double z = (double)k;
    double acc = 0.9999999999998099;
#pragma unroll
    for (int i = 0; i < 8; ++i) acc += CH[i] / (z + (double)(i + 1));
    double t = z + 7.5;
    double g = 2.5066282746310002 * exp((z + 0.5) * log(t) - t) * acc / z;  // Gamma(k)

    double den = g * z;
    par[1] = k;
    par[2] = (float)((double)k / meand);   // 1/theta
    par[3] = (float)(1.0 / den);
#pragma unroll
    for (int j = 1; j < 8; ++j) {
        den *= (z + (double)j);
        par[3 + j] = (float)(1.0 / den);
    }
}

// ============ K3: elementwise apply ============
__global__ void __launch_bounds__(TPB)
k3_apply(const float* __restrict__ x, float* __restrict__ out,
         const void* __restrict__ ws) {
    const int bid  = blockIdx.x;
    const int row  = bid / CHUNKS;
    const int chnk = bid - row * CHUNKS;
    const int tid  = threadIdx.x;
    const float* par = WS_PAR((void*)ws) + row * 12;
    const float rmin = par[0], kk = par[1], invth = par[2];
    const float c0 = par[3], c1 = par[4], c2 = par[5], c3 = par[6];
    const float c4 = par[7], c5 = par[8], c6 = par[9], c7 = par[10];

    const size_t base = (size_t)row * NV4 + (size_t)chnk * CV4;
    const float4* __restrict__ xr = (const float4*)(x) + base;
    float4* __restrict__ yr = (float4*)(out) + base;

#pragma unroll
    for (int j = 0; j < 7; ++j) {
        float4 v = xr[j * TPB + tid];
        float e[4] = {v.x, v.y, v.z, v.w};
        float o[4];
#pragma unroll
        for (int q = 0; q < 4; ++q) {
            float xq = (e[q] - rmin + 1e-7f) * invth;
            float p = fmaf(c7, xq, c6);
            p = fmaf(p, xq, c5);
            p = fmaf(p, xq, c4);
            p = fmaf(p, xq, c3);
            p = fmaf(p, xq, c2);
            p = fmaf(p, xq, c1);
            p = fmaf(p, xq, c0);
            float tt = __expf(fmaf(kk, __logf(xq), -xq));
            float y = tt * p;
            o[q] = isfinite(y) ? y : 0.0f;
        }
        yr[j * TPB + tid] = make_float4(o[0], o[1], o[2], o[3]);
    }
}

extern "C" void kernel_launch(void* const* d_in, const int* in_sizes, int n_in,
                              void* d_out, int out_size, void* d_ws, size_t ws_size,
                              hipStream_t stream) {
    const float* x = (const float*)d_in[0];
    float* out = (float*)d_out;
    const int rows = in_sizes[0] / HW;            // 256
    const int nchunk = rows * CHUNKS;             // 1792

    k1_stats  <<<dim3(nchunk), dim3(TPB), 0, stream>>>(x, d_ws);
    k1b_min   <<<dim3((rows + 63) / 64), dim3(64), 0, stream>>>(d_ws);
    k1c_sumlog<<<dim3(nchunk), dim3(TPB), 0, stream>>>(x, d_ws);
    k2_solve  <<<dim3((rows + 63) / 64), dim3(64), 0, stream>>>(d_ws);
    k3_apply  <<<dim3(nchunk), dim3(TPB), 0, stream>>>(x, out, d_ws);
}